// Round 3
// baseline (654.759 us; speedup 1.0000x reference)
//
#include <hip/hip_runtime.h>

#define T_STEPS 100
#define BATCH   512
#define FIN     784
#define O1      100
#define O2      10

typedef __attribute__((ext_vector_type(4))) double f64x4;

// ---------------------------------------------------------------------------
// K0: f64-MFMA D-layout probe + flag init. One wave. Assumes only the
// universal CDNA conventions A-row = lane&15, B-col = lane&15 (constant
// other operand makes the probe independent of everything else):
//   probe1: A[i][k]=i, B=0.25  -> D[i][j]=i  -> acc[r] = D-row of (lane,reg)
//   probe2: A=0.25, B[k][j]=j  -> D[i][j]=j  -> acc[r] = D-col of (lane,reg)
// If even those assumptions are wrong, k1_check catches it and k1_fallback
// recomputes. maps[l*8+r] = row, maps[l*8+4+r] = col.
// ---------------------------------------------------------------------------
__global__ __launch_bounds__(64) void k0_probe(int* __restrict__ maps,
                                               int* __restrict__ flag) {
  const int l = threadIdx.x;
  if (l == 0) flag[0] = 0;
  const f64x4 z = {0.0, 0.0, 0.0, 0.0};
  f64x4 pr = __builtin_amdgcn_mfma_f64_16x16x4f64((double)(l & 15), 0.25, z, 0, 0, 0);
  f64x4 pc = __builtin_amdgcn_mfma_f64_16x16x4f64(0.25, (double)(l & 15), z, 0, 0, 0);
#pragma unroll
  for (int r = 0; r < 4; ++r) {
    int rm = (int)(pr[r] + 0.5); rm = rm < 0 ? 0 : (rm > 15 ? 15 : rm);
    int cm = (int)(pc[r] + 0.5); cm = cm < 0 ? 0 : (cm > 15 ? 15 : cm);
    maps[l * 8 + r]     = rm;
    maps[l * 8 + 4 + r] = cm;
  }
}

// ---------------------------------------------------------------------------
// K1: fused C-mean + f64 MFMA GEMM, stores through the probed D maps.
//   I1T[t][o][b] = sum_f 0.5*(in[b,t,f,0]+in[b,t,f,1]) * W1[f,o]
// 4 waves/block, each wave owns a 16(o) x 16(b) tile over full K=784.
// A: W1[f][o0+ (l&15)], k-slot l>>4.  B: in-row b0+(l&15), k-slot l>>4.
// Last o-tile overlaps (o0=84): duplicate stores are bitwise identical.
// ---------------------------------------------------------------------------
__global__ __launch_bounds__(256) void k1_mfma(const float* __restrict__ in,
                                               const float* __restrict__ W1,
                                               const int* __restrict__ maps,
                                               double* __restrict__ I1T) {
  const int l   = threadIdx.x & 63;
  const int w   = threadIdx.x >> 6;
  const int r16 = l & 15;
  const int q16 = l >> 4;
  const int o0  = (blockIdx.x < 6) ? (int)blockIdx.x * 16 : 84;
  const int b0  = (int)blockIdx.y * 64 + w * 16;
  const int t   = (int)blockIdx.z;

  const int4 rm = *reinterpret_cast<const int4*>(maps + l * 8);
  const int4 cm = *reinterpret_cast<const int4*>(maps + l * 8 + 4);

  const float* pW = W1 + (size_t)q16 * O1 + (o0 + r16);
  const float2* pI = reinterpret_cast<const float2*>(in) +
                     ((size_t)(b0 + r16) * T_STEPS + t) * FIN + q16;

  f64x4 acc = {0.0, 0.0, 0.0, 0.0};
#pragma unroll 4
  for (int kq = 0; kq < FIN / 4; ++kq) {
    const double a = (double)pW[0];
    const float2 x = pI[0];
    const double b = 0.5 * ((double)x.x + (double)x.y);   // exact f64 C-mean
    acc = __builtin_amdgcn_mfma_f64_16x16x4f64(a, b, acc, 0, 0, 0);
    pW += 4 * O1;
    pI += 4;
  }

  double* base = I1T + (size_t)t * O1 * BATCH;
  base[(size_t)(o0 + rm.x) * BATCH + (b0 + cm.x)] = acc[0];
  base[(size_t)(o0 + rm.y) * BATCH + (b0 + cm.y)] = acc[1];
  base[(size_t)(o0 + rm.z) * BATCH + (b0 + cm.z)] = acc[2];
  base[(size_t)(o0 + rm.w) * BATCH + (b0 + cm.w)] = acc[3];
}

// ---------------------------------------------------------------------------
// K1_CHECK: verify one sampled element of EVERY (t,o) row of I1T against a
// direct f64 dot product. True rounding diff ~1e-12; layout errors are O(0.1).
// ---------------------------------------------------------------------------
__global__ __launch_bounds__(256) void k1_check(const float* __restrict__ in,
                                                const float* __restrict__ W1,
                                                const double* __restrict__ I1T,
                                                int* __restrict__ flag) {
  const int idx = blockIdx.x * 256 + threadIdx.x;
  if (idx >= T_STEPS * O1) return;
  const int t = idx / O1, o = idx - t * O1;
  const int b = (37 * t + 11 * o) & 511;
  const float2* pI = reinterpret_cast<const float2*>(in) + ((size_t)b * T_STEPS + t) * FIN;
  double s = 0.0;
  for (int f = 0; f < FIN; ++f) {
    const float2 x = pI[f];
    s += (double)W1[f * O1 + o] * (0.5 * ((double)x.x + (double)x.y));
  }
  const double got = I1T[((size_t)t * O1 + o) * BATCH + b];
  if (fabs(got - s) > 1e-6 * (fabs(s) + 1.0)) flag[0] = 1;
}

// ---------------------------------------------------------------------------
// K1_FALLBACK: round-1 VALU kernel (verified absmax 0.0), gated on flag.
// Early-exits (~2us) when the MFMA path verified clean.
// ---------------------------------------------------------------------------
#define BM 64
#define KC 16
#define O1P 112
__global__ __launch_bounds__(256) void k1_fallback(const float* __restrict__ in,
                                                   const float* __restrict__ W1,
                                                   double* __restrict__ I1T,
                                                   const int* __restrict__ flag) {
  if (flag[0] == 0) return;   // uniform branch, no divergence
  __shared__ double A_lds[KC][BM + 1];
  __shared__ double W_lds[KC][O1P];
  const int t   = blockIdx.y;
  const int b0  = blockIdx.x * BM;
  const int tid = threadIdx.x;
  const int bt  = tid & 15;
  const int ot  = tid >> 4;

  for (int i = tid; i < KC * (O1P - O1); i += 256) {
    int k = i / (O1P - O1), o = O1 + (i - k * (O1P - O1));
    W_lds[k][o] = 0.0;
  }
  double acc[4][7];
#pragma unroll
  for (int m = 0; m < 4; ++m)
#pragma unroll
    for (int n = 0; n < 7; ++n) acc[m][n] = 0.0;

  for (int kc = 0; kc < FIN / KC; ++kc) {
    __syncthreads();
#pragma unroll
    for (int p = 0; p < 2; ++p) {
      int q  = p * 256 + tid;
      int bl = q >> 3, fq = q & 7;
      int f  = kc * KC + fq * 2;
      const float4 v = *reinterpret_cast<const float4*>(
          &in[(((size_t)(b0 + bl) * T_STEPS + t) * FIN + f) * 2]);
      A_lds[fq * 2 + 0][bl] = 0.5 * ((double)v.x + (double)v.y);
      A_lds[fq * 2 + 1][bl] = 0.5 * ((double)v.z + (double)v.w);
    }
    for (int i = tid; i < KC * O1; i += 256) {
      int k = i / O1, o = i - k * O1;
      W_lds[k][o] = (double)W1[(kc * KC + k) * O1 + o];
    }
    __syncthreads();
#pragma unroll
    for (int k = 0; k < KC; ++k) {
      double a[4], w[7];
#pragma unroll
      for (int m = 0; m < 4; ++m) a[m] = A_lds[k][bt + 16 * m];
#pragma unroll
      for (int n = 0; n < 7; ++n) w[n] = W_lds[k][ot + 16 * n];
#pragma unroll
      for (int m = 0; m < 4; ++m)
#pragma unroll
        for (int n = 0; n < 7; ++n) acc[m][n] += a[m] * w[n];
    }
  }
#pragma unroll
  for (int n = 0; n < 7; ++n) {
    int o = ot + 16 * n;
    if (o < O1) {
#pragma unroll
      for (int m = 0; m < 4; ++m) {
        int b = b0 + bt + 16 * m;
        I1T[((size_t)t * O1 + o) * BATCH + b] = acc[m][n];
      }
    }
  }
}

// ---------------------------------------------------------------------------
// K2: BN stats per (t,o) row: mu, rstd. One wave per row.
// ---------------------------------------------------------------------------
__global__ __launch_bounds__(256) void k2_bnstats(const double* __restrict__ I1T,
                                                  double* __restrict__ mu,
                                                  double* __restrict__ rstd) {
  const int r    = blockIdx.x * 4 + (threadIdx.x >> 6);
  const int lane = threadIdx.x & 63;
  const double2* row2 = reinterpret_cast<const double2*>(I1T + (size_t)r * BATCH) + lane * 4;
  double v[8];
#pragma unroll
  for (int u = 0; u < 4; ++u) {
    double2 p = row2[u];
    v[2 * u] = p.x; v[2 * u + 1] = p.y;
  }
  double s = 0.0;
#pragma unroll
  for (int u = 0; u < 8; ++u) s += v[u];
#pragma unroll
  for (int m = 32; m >= 1; m >>= 1) s += __shfl_xor(s, m, 64);
  const double mean = s / 512.0;
  double q = 0.0;
#pragma unroll
  for (int u = 0; u < 8; ++u) { double d = v[u] - mean; q += d * d; }
#pragma unroll
  for (int m = 32; m >= 1; m >>= 1) q += __shfl_xor(q, m, 64);
  if (lane == 0) {
    mu[r]   = mean;
    rstd[r] = 1.0 / sqrt(q / 512.0 + 1e-5);
  }
}

// ---------------------------------------------------------------------------
// K3: layer-1 LIF scan. Block = o, thread = b.
// ---------------------------------------------------------------------------
__global__ __launch_bounds__(512) void k3_lif1(const double* __restrict__ I1T,
                                               const double* __restrict__ mu,
                                               const double* __restrict__ rstd,
                                               const float* __restrict__ scale,
                                               const float* __restrict__ bias,
                                               float* __restrict__ z1T) {
  const int o = blockIdx.x;
  const int b = threadIdx.x;
  const double sc = (double)scale[o], bs = (double)bias[o];
  double v = 0.0;
  for (int tc = 0; tc < T_STEPS; tc += 10) {
    double x[10], muv[10], rsv[10];
#pragma unroll
    for (int u = 0; u < 10; ++u) {
      const int t = tc + u;
      x[u]   = I1T[((size_t)t * O1 + o) * BATCH + b];
      muv[u] = mu[t * O1 + o];
      rsv[u] = rstd[t * O1 + o];
    }
#pragma unroll
    for (int u = 0; u < 10; ++u) {
      const double i = ((x[u] - muv[u]) * rsv[u]) * sc + bs;
      v = 0.95 * v + i;
      const bool z = (v > 1.0);
      z1T[((size_t)(tc + u) * O1 + o) * BATCH + b] = z ? 1.0f : 0.0f;
      if (z) v = 0.0;
    }
  }
}

// ---------------------------------------------------------------------------
// K4: I2[t][j][b] = sum_o z1T[t][o][b] * W2[o][j].
// ---------------------------------------------------------------------------
__global__ __launch_bounds__(512) void k4_proj2(const float* __restrict__ z1T,
                                                const float* __restrict__ W2,
                                                double* __restrict__ I2) {
  __shared__ double W2_lds[O1 * O2];
  const int t = blockIdx.x;
  const int b = threadIdx.x;
  for (int i = threadIdx.x; i < O1 * O2; i += 512) W2_lds[i] = (double)W2[i];
  __syncthreads();
  double acc[O2];
#pragma unroll
  for (int j = 0; j < O2; ++j) acc[j] = 0.0;
  for (int o = 0; o < O1; ++o) {
    const double z = (double)z1T[((size_t)t * O1 + o) * BATCH + b];
#pragma unroll
    for (int j = 0; j < O2; ++j) acc[j] += z * W2_lds[o * O2 + j];
  }
#pragma unroll
  for (int j = 0; j < O2; ++j)
    I2[((size_t)t * O2 + j) * BATCH + b] = acc[j];
}

// ---------------------------------------------------------------------------
// K5: layer-2 LIF scan + time-mean.
// ---------------------------------------------------------------------------
__global__ __launch_bounds__(512) void k5_lif2(const double* __restrict__ I2,
                                               float* __restrict__ out) {
  const int j = blockIdx.x;
  const int b = threadIdx.x;
  double v = 0.0;
  int cnt = 0;
  for (int tc = 0; tc < T_STEPS; tc += 10) {
    double x[10];
#pragma unroll
    for (int u = 0; u < 10; ++u)
      x[u] = I2[((size_t)(tc + u) * O2 + j) * BATCH + b];
#pragma unroll
    for (int u = 0; u < 10; ++u) {
      v = 0.95 * v + x[u];
      if (v > 1.0) { ++cnt; v = 0.0; }
    }
  }
  out[b * O2 + j] = (float)((double)cnt / 100.0);
}

// ---------------------------------------------------------------------------
extern "C" void kernel_launch(void* const* d_in, const int* in_sizes, int n_in,
                              void* d_out, int out_size, void* d_ws, size_t ws_size,
                              hipStream_t stream) {
  const float* in    = (const float*)d_in[0];
  const float* W1    = (const float*)d_in[2];
  const float* scale = (const float*)d_in[3];
  const float* bias  = (const float*)d_in[4];
  const float* W2    = (const float*)d_in[5];
  float* out = (float*)d_out;

  char* ws = (char*)d_ws;
  size_t off = 0;
  int*    maps = (int*)(ws + off);    off += 4096;  // 2KB maps + flag, padded
  int*    flag = maps + 64 * 8;
  double* I1T  = (double*)(ws + off); off += (size_t)T_STEPS * O1 * BATCH * sizeof(double);
  double* mu   = (double*)(ws + off); off += (size_t)T_STEPS * O1 * sizeof(double);
  double* rstd = (double*)(ws + off); off += (size_t)T_STEPS * O1 * sizeof(double);
  float*  z1T  = (float*)(ws + off);  off += (size_t)T_STEPS * O1 * BATCH * sizeof(float);
  double* I2   = (double*)(ws + off); off += (size_t)T_STEPS * O2 * BATCH * sizeof(double);

  k0_probe   <<<dim3(1), 64, 0, stream>>>(maps, flag);
  k1_mfma    <<<dim3(7, BATCH / 64, T_STEPS), 256, 0, stream>>>(in, W1, maps, I1T);
  k1_check   <<<dim3(40), 256, 0, stream>>>(in, W1, I1T, flag);
  k1_fallback<<<dim3(BATCH / BM, T_STEPS), 256, 0, stream>>>(in, W1, I1T, flag);
  k2_bnstats <<<dim3(T_STEPS * O1 / 4), 256, 0, stream>>>(I1T, mu, rstd);
  k3_lif1    <<<dim3(O1), 512, 0, stream>>>(I1T, mu, rstd, scale, bias, z1T);
  k4_proj2   <<<dim3(T_STEPS), 512, 0, stream>>>(z1T, W2, I2);
  k5_lif2    <<<dim3(O2), 512, 0, stream>>>(I2, out);
}

// Round 4
// 497.465 us; speedup vs baseline: 1.3162x; 1.3162x over previous
//
#include <hip/hip_runtime.h>

#define T_STEPS 100
#define BATCH   512
#define FIN     784
#define O1      100
#define O2      10
#define KC1     28      // K-chunk for k1 (784 = 28 * 28)

typedef __attribute__((ext_vector_type(4))) double f64x4;

// ---------------------------------------------------------------------------
// K0: f64-MFMA D-layout probe (validated in round 3). Assumes only A-row =
// lane&15, B-col = lane&15:
//   probe1: A[i][k]=i, B=0.25 -> D[i][j]=i -> acc[r] = D-row of (lane,reg)
//   probe2: A=0.25, B[k][j]=j -> D[i][j]=j -> acc[r] = D-col of (lane,reg)
// maps[l*8+r] = row, maps[l*8+4+r] = col.
// ---------------------------------------------------------------------------
__global__ __launch_bounds__(64) void k0_probe(int* __restrict__ maps) {
  const int l = threadIdx.x;
  const f64x4 z = {0.0, 0.0, 0.0, 0.0};
  f64x4 pr = __builtin_amdgcn_mfma_f64_16x16x4f64((double)(l & 15), 0.25, z, 0, 0, 0);
  f64x4 pc = __builtin_amdgcn_mfma_f64_16x16x4f64(0.25, (double)(l & 15), z, 0, 0, 0);
#pragma unroll
  for (int r = 0; r < 4; ++r) {
    int rm = (int)(pr[r] + 0.5); rm = rm < 0 ? 0 : (rm > 15 ? 15 : rm);
    int cm = (int)(pc[r] + 0.5); cm = cm < 0 ? 0 : (cm > 15 ? 15 : cm);
    maps[l * 8 + r]     = rm;
    maps[l * 8 + 4 + r] = cm;
  }
}

// ---------------------------------------------------------------------------
// K1 v2: fused C-mean + f64 MFMA GEMM, input read from HBM exactly once.
//   I1T[t][o][b] = sum_f 0.5*(in[b,t,f,0]+in[b,t,f,1]) * W1[f,o]
// Block = (64 b-rows, one t), covers ALL o via 7 o-tiles {0,16,..,80,84}
// (last tile overlaps -> duplicate stores bitwise identical, zero guards).
// 4 waves; wave w owns b-rows b0+16w..+15. Per K-chunk (28): stage
// C-meaned input (f64) + W1 (f64) in LDS, then 7 quads x (1 B-read +
// 7 A-reads + 7 independent MFMAs). LDS 37 KB -> 4 blocks/CU.
// Bank spread: AI rows padded to 65 f64; frag reads land 4 lanes/bank
// (b64 minimum) for both arrays.
// ---------------------------------------------------------------------------
__global__ __launch_bounds__(256) void k1_mfma(const float* __restrict__ in,
                                               const float* __restrict__ W1,
                                               const int* __restrict__ maps,
                                               double* __restrict__ I1T) {
  __shared__ double AI[KC1][65];    // [f-in-chunk][b]  C-meaned input
  __shared__ double WS[KC1][O1];    // [f-in-chunk][o]  W1 as f64
  const int tid = threadIdx.x;
  const int l   = tid & 63;
  const int w   = tid >> 6;
  const int r16 = l & 15;
  const int q16 = l >> 4;
  const int b0  = (int)blockIdx.x * 64;
  const int t   = (int)blockIdx.y;

  const int4 rm = *reinterpret_cast<const int4*>(maps + l * 8);
  const int4 cm = *reinterpret_cast<const int4*>(maps + l * 8 + 4);

  f64x4 acc[7];
#pragma unroll
  for (int n = 0; n < 7; ++n) acc[n] = (f64x4){0.0, 0.0, 0.0, 0.0};

  for (int c = 0; c < FIN / KC1; ++c) {
    __syncthreads();   // previous chunk's compute done before LDS rewrite
    // stage input: 64 rows x 28 f x 2 c = 896 float4 (16B aligned, coalesced)
    for (int i = tid; i < 896; i += 256) {
      const int row = i / 14, q = i - row * 14;       // q = float4 within row
      const float4 v = *reinterpret_cast<const float4*>(
          in + ((size_t)(b0 + row) * T_STEPS + t) * (FIN * 2) + c * 56 + q * 4);
      AI[q * 2 + 0][row] = 0.5 * ((double)v.x + (double)v.y);  // exact f64 C-mean
      AI[q * 2 + 1][row] = 0.5 * ((double)v.z + (double)v.w);
    }
    // stage W1: 28 x 100 f32, coalesced
    for (int i = tid; i < KC1 * O1; i += 256) {
      const int k = i / O1, o = i - k * O1;
      WS[k][o] = (double)W1[(c * KC1 + k) * O1 + o];
    }
    __syncthreads();
#pragma unroll
    for (int q = 0; q < KC1 / 4; ++q) {
      const double bv = AI[q * 4 + q16][w * 16 + r16];
      const double* wr = &WS[q * 4 + q16][r16];
      acc[0] = __builtin_amdgcn_mfma_f64_16x16x4f64(wr[0],  bv, acc[0], 0, 0, 0);
      acc[1] = __builtin_amdgcn_mfma_f64_16x16x4f64(wr[16], bv, acc[1], 0, 0, 0);
      acc[2] = __builtin_amdgcn_mfma_f64_16x16x4f64(wr[32], bv, acc[2], 0, 0, 0);
      acc[3] = __builtin_amdgcn_mfma_f64_16x16x4f64(wr[48], bv, acc[3], 0, 0, 0);
      acc[4] = __builtin_amdgcn_mfma_f64_16x16x4f64(wr[64], bv, acc[4], 0, 0, 0);
      acc[5] = __builtin_amdgcn_mfma_f64_16x16x4f64(wr[80], bv, acc[5], 0, 0, 0);
      acc[6] = __builtin_amdgcn_mfma_f64_16x16x4f64(wr[84], bv, acc[6], 0, 0, 0);
    }
  }

  double* base = I1T + (size_t)t * O1 * BATCH + (b0 + w * 16);
  const int otab[7] = {0, 16, 32, 48, 64, 80, 84};
#pragma unroll
  for (int n = 0; n < 7; ++n) {
    const int o0 = otab[n];
    base[(size_t)(o0 + rm.x) * BATCH + cm.x] = acc[n][0];
    base[(size_t)(o0 + rm.y) * BATCH + cm.y] = acc[n][1];
    base[(size_t)(o0 + rm.z) * BATCH + cm.z] = acc[n][2];
    base[(size_t)(o0 + rm.w) * BATCH + cm.w] = acc[n][3];
  }
}

// ---------------------------------------------------------------------------
// K2: BN stats per (t,o) row: mu, rstd. One wave per row.
// ---------------------------------------------------------------------------
__global__ __launch_bounds__(256) void k2_bnstats(const double* __restrict__ I1T,
                                                  double* __restrict__ mu,
                                                  double* __restrict__ rstd) {
  const int r    = blockIdx.x * 4 + (threadIdx.x >> 6);
  const int lane = threadIdx.x & 63;
  const double2* row2 = reinterpret_cast<const double2*>(I1T + (size_t)r * BATCH) + lane * 4;
  double v[8];
#pragma unroll
  for (int u = 0; u < 4; ++u) {
    double2 p = row2[u];
    v[2 * u] = p.x; v[2 * u + 1] = p.y;
  }
  double s = 0.0;
#pragma unroll
  for (int u = 0; u < 8; ++u) s += v[u];
#pragma unroll
  for (int m = 32; m >= 1; m >>= 1) s += __shfl_xor(s, m, 64);
  const double mean = s / 512.0;
  double q = 0.0;
#pragma unroll
  for (int u = 0; u < 8; ++u) { double d = v[u] - mean; q += d * d; }
#pragma unroll
  for (int m = 32; m >= 1; m >>= 1) q += __shfl_xor(q, m, 64);
  if (lane == 0) {
    mu[r]   = mean;
    rstd[r] = 1.0 / sqrt(q / 512.0 + 1e-5);
  }
}

// ---------------------------------------------------------------------------
// K3: layer-1 LIF scan. Block = o, thread = b.
// ---------------------------------------------------------------------------
__global__ __launch_bounds__(512) void k3_lif1(const double* __restrict__ I1T,
                                               const double* __restrict__ mu,
                                               const double* __restrict__ rstd,
                                               const float* __restrict__ scale,
                                               const float* __restrict__ bias,
                                               float* __restrict__ z1T) {
  const int o = blockIdx.x;
  const int b = threadIdx.x;
  const double sc = (double)scale[o], bs = (double)bias[o];
  double v = 0.0;
  for (int tc = 0; tc < T_STEPS; tc += 10) {
    double x[10], muv[10], rsv[10];
#pragma unroll
    for (int u = 0; u < 10; ++u) {
      const int t = tc + u;
      x[u]   = I1T[((size_t)t * O1 + o) * BATCH + b];
      muv[u] = mu[t * O1 + o];
      rsv[u] = rstd[t * O1 + o];
    }
#pragma unroll
    for (int u = 0; u < 10; ++u) {
      const double i = ((x[u] - muv[u]) * rsv[u]) * sc + bs;
      v = 0.95 * v + i;
      const bool z = (v > 1.0);
      z1T[((size_t)(tc + u) * O1 + o) * BATCH + b] = z ? 1.0f : 0.0f;
      if (z) v = 0.0;
    }
  }
}

// ---------------------------------------------------------------------------
// K4: I2[t][j][b] = sum_o z1T[t][o][b] * W2[o][j].
// ---------------------------------------------------------------------------
__global__ __launch_bounds__(512) void k4_proj2(const float* __restrict__ z1T,
                                                const float* __restrict__ W2,
                                                double* __restrict__ I2) {
  __shared__ double W2_lds[O1 * O2];
  const int t = blockIdx.x;
  const int b = threadIdx.x;
  for (int i = threadIdx.x; i < O1 * O2; i += 512) W2_lds[i] = (double)W2[i];
  __syncthreads();
  double acc[O2];
#pragma unroll
  for (int j = 0; j < O2; ++j) acc[j] = 0.0;
  for (int o = 0; o < O1; ++o) {
    const double z = (double)z1T[((size_t)t * O1 + o) * BATCH + b];
#pragma unroll
    for (int j = 0; j < O2; ++j) acc[j] += z * W2_lds[o * O2 + j];
  }
#pragma unroll
  for (int j = 0; j < O2; ++j)
    I2[((size_t)t * O2 + j) * BATCH + b] = acc[j];
}

// ---------------------------------------------------------------------------
// K5: layer-2 LIF scan + time-mean.
// ---------------------------------------------------------------------------
__global__ __launch_bounds__(512) void k5_lif2(const double* __restrict__ I2,
                                               float* __restrict__ out) {
  const int j = blockIdx.x;
  const int b = threadIdx.x;
  double v = 0.0;
  int cnt = 0;
  for (int tc = 0; tc < T_STEPS; tc += 10) {
    double x[10];
#pragma unroll
    for (int u = 0; u < 10; ++u)
      x[u] = I2[((size_t)(tc + u) * O2 + j) * BATCH + b];
#pragma unroll
    for (int u = 0; u < 10; ++u) {
      v = 0.95 * v + x[u];
      if (v > 1.0) { ++cnt; v = 0.0; }
    }
  }
  out[b * O2 + j] = (float)((double)cnt / 100.0);
}

// ---------------------------------------------------------------------------
extern "C" void kernel_launch(void* const* d_in, const int* in_sizes, int n_in,
                              void* d_out, int out_size, void* d_ws, size_t ws_size,
                              hipStream_t stream) {
  const float* in    = (const float*)d_in[0];
  const float* W1    = (const float*)d_in[2];
  const float* scale = (const float*)d_in[3];
  const float* bias  = (const float*)d_in[4];
  const float* W2    = (const float*)d_in[5];
  float* out = (float*)d_out;

  char* ws = (char*)d_ws;
  size_t off = 0;
  int*    maps = (int*)(ws + off);    off += 4096;
  double* I1T  = (double*)(ws + off); off += (size_t)T_STEPS * O1 * BATCH * sizeof(double);
  double* mu   = (double*)(ws + off); off += (size_t)T_STEPS * O1 * sizeof(double);
  double* rstd = (double*)(ws + off); off += (size_t)T_STEPS * O1 * sizeof(double);
  float*  z1T  = (float*)(ws + off);  off += (size_t)T_STEPS * O1 * BATCH * sizeof(float);
  double* I2   = (double*)(ws + off); off += (size_t)T_STEPS * O2 * BATCH * sizeof(double);

  k0_probe  <<<dim3(1), 64, 0, stream>>>(maps);
  k1_mfma   <<<dim3(BATCH / 64, T_STEPS), 256, 0, stream>>>(in, W1, maps, I1T);
  k2_bnstats<<<dim3(T_STEPS * O1 / 4), 256, 0, stream>>>(I1T, mu, rstd);
  k3_lif1   <<<dim3(O1), 512, 0, stream>>>(I1T, mu, rstd, scale, bias, z1T);
  k4_proj2  <<<dim3(T_STEPS), 512, 0, stream>>>(z1T, W2, I2);
  k5_lif2   <<<dim3(O2), 512, 0, stream>>>(I2, out);
}